// Round 17
// baseline (106.705 us; speedup 1.0000x reference)
//
#include <hip/hip_runtime.h>

#define BB 48
#define NN 256
#define EE 1024
#define DD 256
#define CIN 256

typedef __attribute__((ext_vector_type(4))) float f32x4;
typedef __attribute__((ext_vector_type(8))) _Float16 f16x8;
typedef __attribute__((ext_vector_type(4))) _Float16 f16x4;

__device__ __forceinline__ float lrelu(float t) { return t >= 0.0f ? t : 0.2f * t; }

__device__ __forceinline__ void gload16(const void* g, void* l) {
  __builtin_amdgcn_global_load_lds((const __attribute__((address_space(1))) void*)g,
                                   (__attribute__((address_space(3))) void*)l, 16, 0, 0);
}

// ---- k_prep: w2s hi/lo, incT, wt16, inc16, wa, xt (all input-only) ----
__global__ __launch_bounds__(256) void k_prep(const float* __restrict__ inc, const float* __restrict__ W2,
                                              const float* __restrict__ W, const float* __restrict__ x,
                                              const float* __restrict__ m, const float* __restrict__ hid,
                                              const float* __restrict__ a, const float* __restrict__ a2,
                                              _Float16* __restrict__ incT, _Float16* __restrict__ w2shi,
                                              _Float16* __restrict__ w2slo, _Float16* __restrict__ wt16,
                                              _Float16* __restrict__ inc16, float* __restrict__ wa,
                                              _Float16* __restrict__ xt) {
  __shared__ float tile[64][65];
  __shared__ float aux[4][64];
  __shared__ float aux2[64];
  int bid = blockIdx.x;
  int t = threadIdx.x;
  if (bid < 256) {  // w2s[e,f] = W2[f,e]*invdeg[f], hi/lo fp16 split
    int f0 = (bid & 15) * 64, e0 = (bid >> 4) * 64;
    int c = t & 63, r = t >> 6;
    {
      float s = 0.f;
      for (int i = 0; i < 64; ++i) s += inc[(size_t)(r * 64 + i) * EE + f0 + c];
      aux[r][c] = s;
    }
#pragma unroll
    for (int i = 0; i < 16; ++i) tile[r + i * 4][c] = W2[(size_t)(f0 + r + i * 4) * EE + e0 + c];
    __syncthreads();
    if (t < 64) aux2[t] = 1.0f / (aux[0][t] + aux[1][t] + aux[2][t] + aux[3][t]);
    __syncthreads();
#pragma unroll
    for (int i = 0; i < 16; ++i) {
      int row = r + i * 4;
      float v = tile[c][row] * aux2[c];
      _Float16 hh = (_Float16)v;
      w2shi[(size_t)(e0 + row) * EE + f0 + c] = hh;
      w2slo[(size_t)(e0 + row) * EE + f0 + c] = (_Float16)(v - (float)hh);
    }
  } else if (bid < 320) {  // incT[e,n] = inc[n,e]
    int s = bid - 256;
    int e0 = (s & 15) * 64, n0 = (s >> 4) * 64;
    int c = t & 63, r = t >> 6;
#pragma unroll
    for (int i = 0; i < 16; ++i) tile[r + i * 4][c] = inc[(size_t)(n0 + r + i * 4) * EE + e0 + c];
    __syncthreads();
#pragma unroll
    for (int i = 0; i < 16; ++i) {
      int row = r + i * 4;
      incT[(size_t)(e0 + row) * NN + n0 + c] = (_Float16)tile[c][row];
    }
  } else if (bid < 336) {  // wt16[d,c] = fp16(W[c,d])
    int s = bid - 320;
    int c0 = (s & 3) * 64, d0 = (s >> 2) * 64;
    int c = t & 63, r = t >> 6;
#pragma unroll
    for (int i = 0; i < 16; ++i) tile[r + i * 4][c] = W[(size_t)(c0 + r + i * 4) * DD + d0 + c];
    __syncthreads();
#pragma unroll
    for (int i = 0; i < 16; ++i) {
      int row = r + i * 4;
      wt16[(size_t)(d0 + row) * CIN + c0 + c] = (_Float16)tile[c][row];
    }
  } else if (bid < 352) {  // inc16[n,f] = fp16(inc) (exact 0/1)
    int s = bid - 336;
    size_t base = ((size_t)s * 256 + t) * 64;
#pragma unroll
    for (int i = 0; i < 16; ++i) {
      f32x4 v = *(const f32x4*)&inc[base + i * 4];
      f16x4 o;
      o[0] = (_Float16)v[0];
      o[1] = (_Float16)v[1];
      o[2] = (_Float16)v[2];
      o[3] = (_Float16)v[3];
      *(f16x4*)&inc16[base + i * 4] = o;
    }
  } else if (bid < 608) {  // wa
    float(*red)[4] = (float(*)[4])aux;
    int c = bid - 352;
    int l = t & 63, wv = t >> 6;
    float w = W[(size_t)c * DD + t];
    float p0 = w * a[t], p1 = w * a[DD + t], p2 = w * a2[t];
#pragma unroll
    for (int off = 32; off > 0; off >>= 1) {
      p0 += __shfl_down(p0, off);
      p1 += __shfl_down(p1, off);
      p2 += __shfl_down(p2, off);
    }
    if (l == 0) {
      red[0][wv] = p0;
      red[1][wv] = p1;
      red[2][wv] = p2;
    }
    __syncthreads();
    if (t == 0) wa[c] = red[0][0] + red[0][1] + red[0][2] + red[0][3];
    if (t == 1) wa[256 + c] = red[1][0] + red[1][1] + red[1][2] + red[1][3];
    if (t == 2) wa[512 + c] = red[2][0] + red[2][1] + red[2][2] + red[2][3];
    if (c == 0) {
      __syncthreads();
      float q0 = a[t], q1 = a[DD + t], q2 = a2[t];
#pragma unroll
      for (int off = 32; off > 0; off >>= 1) {
        q0 += __shfl_down(q0, off);
        q1 += __shfl_down(q1, off);
        q2 += __shfl_down(q2, off);
      }
      if (l == 0) {
        red[0][wv] = q0;
        red[1][wv] = q1;
        red[2][wv] = q2;
      }
      __syncthreads();
      if (t == 0) wa[768] = red[0][0] + red[0][1] + red[0][2] + red[0][3];
      if (t == 1) wa[769] = red[1][0] + red[1][1] + red[1][2] + red[1][3];
      if (t == 2) wa[770] = red[2][0] + red[2][1] + red[2][2] + red[2][3];
    }
  } else {  // xt16[b,n,c] = fp16(x_in[b,c,n]); 768 blocks
    int s = bid - 608;
    int c0 = (s & 3) * 64, n0 = ((s >> 2) & 3) * 64, b = s >> 4;
    int c = t & 63, r = t >> 6;
#pragma unroll
    for (int i = 0; i < 16; ++i) {
      int ch = c0 + r + i * 4;
      const float* row;
      if (ch < 96) row = x + ((size_t)b * 96 + ch) * NN;
      else if (ch < 192) row = m + ((size_t)b * 96 + (ch - 96)) * NN;
      else row = hid + ((size_t)b * 64 + (ch - 192)) * NN;
      tile[r + i * 4][c] = row[n0 + c];
    }
    __syncthreads();
#pragma unroll
    for (int i = 0; i < 16; ++i) {
      int row = r + i * 4;
      xt[((size_t)b * NN + n0 + row) * CIN + c0 + c] = (_Float16)tile[c][row];
    }
  }
}

// ---- k_mid: h16 (768) + M32/M16 2-term split MFMA (64) + ns2 (48) ----
__global__ __launch_bounds__(256) void k_mid(const _Float16* __restrict__ xt, const _Float16* __restrict__ wt,
                                             const float* __restrict__ bias, _Float16* __restrict__ hThi,
                                             const _Float16* __restrict__ inc16, const _Float16* __restrict__ w2shi,
                                             const _Float16* __restrict__ w2slo, float* __restrict__ M32,
                                             _Float16* __restrict__ M16, const float* __restrict__ x,
                                             const float* __restrict__ m, const float* __restrict__ hid,
                                             const float* __restrict__ wa, float* __restrict__ node_sc,
                                             float* __restrict__ g1, float* __restrict__ g2) {
  __shared__ _Float16 smA[64 * 64];
  __shared__ _Float16 smB[64 * 64];
  __shared__ _Float16 smB2[64 * 64];
  int bid = blockIdx.x;
  int t = threadIdx.x;
  if (bid < 768) {  // h16
    int xcd = bid & 7, il = bid >> 3;
    int ntile = il & 3, dtile = (il >> 2) & 3, bl = il >> 4;
    int b = xcd * 6 + bl;
    int n0 = ntile * 64, d0 = dtile * 64;
    int w = t >> 6, l = t & 63;
    int wm = w >> 1, wn = w & 1;
    int lr = l & 15;
    const _Float16* A = xt + ((size_t)b * NN + n0) * CIN;
    const _Float16* Bp = wt + (size_t)d0 * CIN;
    int lrow = l >> 3;
    int scol = 8 * ((l & 7) ^ (lrow & 7));
    f32x4 acc[2][2];
    f32x4 z = {0.f, 0.f, 0.f, 0.f};
#pragma unroll
    for (int i = 0; i < 2; ++i)
#pragma unroll
      for (int j = 0; j < 2; ++j) acc[i][j] = z;
    for (int kk = 0; kk < CIN; kk += 64) {
#pragma unroll
      for (int q = 0; q < 2; ++q) {
        int row = q * 32 + w * 8 + lrow;
        int lb = (q * 32 + w * 8) * 64;
        gload16(A + (size_t)row * CIN + kk + scol, smA + lb);
        gload16(Bp + (size_t)row * CIN + kk + scol, smB + lb);
      }
      __syncthreads();
      f16x8 af[2][2], bf[2][2];
#pragma unroll
      for (int i = 0; i < 2; ++i)
#pragma unroll
        for (int ks = 0; ks < 2; ++ks) {
          int ra = wm * 32 + i * 16 + lr;
          af[i][ks] = *(const f16x8*)&smA[ra * 64 + ((ks * 32 + (l >> 4) * 8) ^ ((ra & 7) << 3))];
          int rb = wn * 32 + i * 16 + lr;
          bf[i][ks] = *(const f16x8*)&smB[rb * 64 + ((ks * 32 + (l >> 4) * 8) ^ ((rb & 7) << 3))];
        }
#pragma unroll
      for (int ks = 0; ks < 2; ++ks)
#pragma unroll
        for (int i = 0; i < 2; ++i)
#pragma unroll
          for (int j = 0; j < 2; ++j)
            acc[i][j] = __builtin_amdgcn_mfma_f32_16x16x32_f16(af[i][ks], bf[j][ks], acc[i][j], 0, 0, 0);
      __syncthreads();
    }
#pragma unroll
    for (int i = 0; i < 2; ++i)
#pragma unroll
      for (int j = 0; j < 2; ++j) {
        int nb = n0 + wm * 32 + i * 16 + (l >> 4) * 4;
        int d = d0 + wn * 32 + j * 16 + lr;
        float4 bv = *(const float4*)&bias[nb];
        f16x4 vh;
        vh[0] = (_Float16)(acc[i][j][0] + bv.x);
        vh[1] = (_Float16)(acc[i][j][1] + bv.y);
        vh[2] = (_Float16)(acc[i][j][2] + bv.z);
        vh[3] = (_Float16)(acc[i][j][3] + bv.w);
        *(f16x4*)&hThi[((size_t)b * DD + d) * NN + nb] = vh;
      }
  } else if (bid < 832) {  // M32/M16[e,n] = sum_f inc16[n,f]*(w2shi+w2slo)[e,f]; 64 blocks
    int mb = bid - 768;
    int np = mb & 3, ep = mb >> 2;
    int m0 = np * 64;
    int n0 = ep * 64;
    int w = t >> 6, l = t & 63;
    int wm = w >> 1, wn = w & 1;
    int lr = l & 15;
    const _Float16* A = inc16 + (size_t)m0 * EE;
    const _Float16* Bh = w2shi + (size_t)n0 * EE;
    const _Float16* Bl = w2slo + (size_t)n0 * EE;
    int lrow = l >> 3;
    int scol = 8 * ((l & 7) ^ (lrow & 7));
    f32x4 acc[2][2];
    f32x4 z = {0.f, 0.f, 0.f, 0.f};
#pragma unroll
    for (int i = 0; i < 2; ++i)
#pragma unroll
      for (int j = 0; j < 2; ++j) acc[i][j] = z;
    for (int kk = 0; kk < EE; kk += 64) {
#pragma unroll
      for (int q = 0; q < 2; ++q) {
        int row = q * 32 + w * 8 + lrow;
        int lb = (q * 32 + w * 8) * 64;
        gload16(A + (size_t)row * EE + kk + scol, smA + lb);
        gload16(Bh + (size_t)row * EE + kk + scol, smB + lb);
        gload16(Bl + (size_t)row * EE + kk + scol, smB2 + lb);
      }
      __syncthreads();
      f16x8 af[2][2], bfh[2][2], bfl[2][2];
#pragma unroll
      for (int i = 0; i < 2; ++i)
#pragma unroll
        for (int ks = 0; ks < 2; ++ks) {
          int ra = wm * 32 + i * 16 + lr;
          int off_a = ra * 64 + ((ks * 32 + (l >> 4) * 8) ^ ((ra & 7) << 3));
          af[i][ks] = *(const f16x8*)&smA[off_a];
          int rb = wn * 32 + i * 16 + lr;
          int off_b = rb * 64 + ((ks * 32 + (l >> 4) * 8) ^ ((rb & 7) << 3));
          bfh[i][ks] = *(const f16x8*)&smB[off_b];
          bfl[i][ks] = *(const f16x8*)&smB2[off_b];
        }
#pragma unroll
      for (int ks = 0; ks < 2; ++ks)
#pragma unroll
        for (int i = 0; i < 2; ++i)
#pragma unroll
          for (int j = 0; j < 2; ++j) {
            acc[i][j] = __builtin_amdgcn_mfma_f32_16x16x32_f16(af[i][ks], bfh[j][ks], acc[i][j], 0, 0, 0);
            acc[i][j] = __builtin_amdgcn_mfma_f32_16x16x32_f16(af[i][ks], bfl[j][ks], acc[i][j], 0, 0, 0);
          }
      __syncthreads();
    }
#pragma unroll
    for (int i = 0; i < 2; ++i)
#pragma unroll
      for (int j = 0; j < 2; ++j) {
        int n = m0 + wm * 32 + i * 16 + (l >> 4) * 4;
        int e = n0 + wn * 32 + j * 16 + lr;
        *(f32x4*)&M32[(size_t)e * NN + n] = acc[i][j];
        f16x4 v;
#pragma unroll
        for (int r = 0; r < 4; ++r) v[r] = (_Float16)acc[i][j][r];
        *(f16x4*)&M16[(size_t)e * NN + n] = v;
      }
  } else {  // ns2: b = bid - 832
    float* s0a = (float*)smA;
    float* s1a = s0a + 256;
    float* s2a = s0a + 512;
    int b = bid - 832;
    s0a[t] = wa[t];
    s1a[t] = wa[256 + t];
    s2a[t] = wa[512 + t];
    __syncthreads();
    float s0 = 0.f, s1 = 0.f, s2 = 0.f;
#pragma unroll 4
    for (int c = 0; c < 256; ++c) {
      const float* row;
      if (c < 96) row = x + ((size_t)b * 96 + c) * NN;
      else if (c < 192) row = m + ((size_t)b * 96 + (c - 96)) * NN;
      else row = hid + ((size_t)b * 64 + (c - 192)) * NN;
      float v = row[t];
      s0 += v * s0a[c];
      s1 += v * s1a[c];
      s2 += v * s2a[c];
    }
    float bv = bias[t];
    int idx = b * NN + t;
    node_sc[idx] = s0 + bv * wa[768];
    g1[idx] = s1 + bv * wa[769];
    g2[idx] = s2 + bv * wa[770];
  }
}

// ---- k_out1s: score/att16 (768 blocks FIRST) + out1/out1T16 GEMM (1536 blocks, 64e x 128d) ----
// att16/out1T16 are PANEL-BLOCKED: [b][ep][n or d][64e] — contiguous per-block writes
__global__ __launch_bounds__(256) void k_out1s(const _Float16* __restrict__ M16, const _Float16* __restrict__ hThi,
                                               float* __restrict__ out1, _Float16* __restrict__ out1T,
                                               const float* __restrict__ M32, const float* __restrict__ g1,
                                               const float* __restrict__ g2, const float* __restrict__ node_sc,
                                               const float* __restrict__ pri_e, const float* __restrict__ a2,
                                               const float* __restrict__ a3, const _Float16* __restrict__ incT,
                                               const float* __restrict__ inc, _Float16* __restrict__ att16) {
  __shared__ _Float16 smA[64 * 64];
  __shared__ _Float16 smB[128 * 64];
  int bid = blockIdx.x;
  int t = threadIdx.x;
  if (bid >= 768) {  // out1[b,e,d] = sum_n M16[e,n]*hThi[b,d,n]; 64e x 128d; b-pinned XCD
    int gb = bid - 768;
    int xcd = gb & 7, il = gb >> 3;  // 192 per XCD
    int ep = il & 15, dblk = (il >> 4) & 1, bl = il >> 5;
    int b = xcd * 6 + bl;
    int e0 = ep * 64, d0 = dblk * 128;
    int w = t >> 6, l = t & 63;
    int wm = w >> 1, wn = w & 1;
    int lr = l & 15;
    const _Float16* A = M16 + (size_t)e0 * NN;
    const _Float16* Bp = hThi + ((size_t)b * DD + d0) * NN;
    int lrow = l >> 3;
    int scol = 8 * ((l & 7) ^ (lrow & 7));
    f32x4 acc[2][4];
    f32x4 z = {0.f, 0.f, 0.f, 0.f};
#pragma unroll
    for (int i = 0; i < 2; ++i)
#pragma unroll
      for (int j = 0; j < 4; ++j) acc[i][j] = z;
    for (int kk = 0; kk < NN; kk += 64) {
#pragma unroll
      for (int q = 0; q < 2; ++q) {  // A: 64 rows
        int row = q * 32 + w * 8 + lrow;
        int lb = (q * 32 + w * 8) * 64;
        gload16(A + (size_t)row * NN + kk + scol, smA + lb);
      }
#pragma unroll
      for (int q = 0; q < 4; ++q) {  // B: 128 rows
        int row = q * 32 + w * 8 + lrow;
        int lb = (q * 32 + w * 8) * 64;
        gload16(Bp + (size_t)row * NN + kk + scol, smB + lb);
      }
      __syncthreads();
      f16x8 af[2][2], bf[4][2];
#pragma unroll
      for (int i = 0; i < 2; ++i)
#pragma unroll
        for (int ks = 0; ks < 2; ++ks) {
          int ra = wm * 32 + i * 16 + lr;
          af[i][ks] = *(const f16x8*)&smA[ra * 64 + ((ks * 32 + (l >> 4) * 8) ^ ((ra & 7) << 3))];
        }
#pragma unroll
      for (int j = 0; j < 4; ++j)
#pragma unroll
        for (int ks = 0; ks < 2; ++ks) {
          int rb = wn * 64 + j * 16 + lr;
          bf[j][ks] = *(const f16x8*)&smB[rb * 64 + ((ks * 32 + (l >> 4) * 8) ^ ((rb & 7) << 3))];
        }
#pragma unroll
      for (int ks = 0; ks < 2; ++ks)
#pragma unroll
        for (int i = 0; i < 2; ++i)
#pragma unroll
          for (int j = 0; j < 4; ++j)
            acc[i][j] = __builtin_amdgcn_mfma_f32_16x16x32_f16(af[i][ks], bf[j][ks], acc[i][j], 0, 0, 0);
      __syncthreads();
    }
    // out1 fp32 nontemporal stores (write-once, never re-read)
#pragma unroll
    for (int i = 0; i < 2; ++i)
#pragma unroll
      for (int j = 0; j < 4; ++j) {
        int e = e0 + wm * 32 + i * 16 + (l >> 4) * 4;
        int d = d0 + wn * 64 + j * 16 + lr;
#pragma unroll
        for (int r = 0; r < 4; ++r)
          __builtin_nontemporal_store(acc[i][j][r], &out1[((size_t)b * EE + e + r) * DD + d]);
      }
    // out1T16 via LDS (smB dead) -> panel-blocked [b][ep][d(256)][64e]: contiguous 16KB
#pragma unroll
    for (int i = 0; i < 2; ++i)
#pragma unroll
      for (int j = 0; j < 4; ++j) {
        int dr = wn * 64 + j * 16 + lr;
        int er = wm * 32 + i * 16 + (l >> 4) * 4;
        f16x4 v16;
#pragma unroll
        for (int r = 0; r < 4; ++r) v16[r] = (_Float16)acc[i][j][r];
        *(f16x4*)&smB[dr * 64 + (er ^ ((dr & 7) << 3))] = v16;
      }
    __syncthreads();
    {
      int dr = t >> 1, ec = (t & 1) * 32;
      _Float16* orow = out1T + (((size_t)b * 16 + ep) * 256 + d0 + dr) * 64;
#pragma unroll
      for (int g = 0; g < 4; ++g) {
        int e8 = ec + g * 8;
        f16x8 v = *(const f16x8*)&smB[dr * 64 + (e8 ^ ((dr & 7) << 3))];
        *(f16x8*)&orow[e8] = v;
      }
    }
  } else {  // score + att16 (dispatched first)
    float* sg1 = (float*)smA;                  // 256
    float* sg2 = sg1 + 256;                    // 256
    float* snc = sg2 + 256;                    // 256
    float(*r1)[4] = (float(*)[4])(snc + 256);  // 64*4
    float(*r2)[4] = r1 + 64;                   // 64*4
    float* sesc = (float*)(r2 + 64);           // 64
    float* steA = sesc + 64;                   // 64
    float* srm = steA + 64;                    // 64
    float* sri = srm + 64;                     // 64
    int sb = bid;
    int sep = sb & 15;
    int e0p = sep * 64, b = sb >> 4;
    float a30 = a3[0], a31 = a3[1];
    sg1[t] = g1[b * NN + t];
    sg2[t] = g2[b * NN + t];
    snc[t] = node_sc[b * NN + t];
    __syncthreads();
    {  // phase 1: esc/te for 64 e's (fp32-exact via M32)
      int ei = t >> 2, part = t & 3;
      const float* Mr = M32 + (size_t)(e0p + ei) * NN + part * 64;
      const float* pg1 = sg1 + part * 64;
      const float* pg2 = sg2 + part * 64;
      float s1 = 0.f, s2 = 0.f;
      for (int i = 0; i < 64; i += 4) {
        f32x4 mv = *(const f32x4*)&Mr[i];
        f32x4 v1 = *(const f32x4*)&pg1[i];
        f32x4 v2 = *(const f32x4*)&pg2[i];
        s1 += mv[0] * v1[0] + mv[1] * v1[1] + mv[2] * v1[2] + mv[3] * v1[3];
        s2 += mv[0] * v2[0] + mv[1] * v2[1] + mv[2] * v2[2] + mv[3] * v2[3];
      }
      r1[ei][part] = s1;
      r2[ei][part] = s2;
    }
    __syncthreads();
    if (t < 64) {
      int row = b * EE + e0p + t;
      float es = r1[t][0] + r1[t][1] + r1[t][2] + r1[t][3];
      float te = lrelu(r2[t][0] + r2[t][1] + r2[t][2] + r2[t][3] + pri_e[row] * a2[DD]);
      sesc[t] = es;
      steA[t] = te * a30;
    }
    __syncthreads();
    {  // phase 2: masked max + exp-sum per e (wave per row)
      int w = t >> 6, l = t & 63;
      for (int rr = 0; rr < 16; ++rr) {
        int er = w * 16 + rr;
        int e = e0p + er;
        float es = sesc[er], ta = steA[er];
        f16x4 ic = *(const f16x4*)&incT[(size_t)e * NN + l * 4];
        float s2v[4];
        bool msk[4];
        float vmax = -3.0e38f;
#pragma unroll
        for (int q = 0; q < 4; ++q) {
          float s1 = lrelu(snc[l * 4 + q] + es);
          float s2 = lrelu(ta + s1 * a31);
          msk[q] = (float)ic[q] > 0.f;
          s2v[q] = s2;
          if (msk[q]) vmax = fmaxf(vmax, s2);
        }
#pragma unroll
        for (int off = 32; off > 0; off >>= 1) vmax = fmaxf(vmax, __shfl_xor(vmax, off));
        float ss = 0.f;
#pragma unroll
        for (int q = 0; q < 4; ++q)
          if (msk[q]) ss += __expf(s2v[q] - vmax);
#pragma unroll
        for (int off = 32; off > 0; off >>= 1) ss += __shfl_xor(ss, off);
        if (l == 0) {
          srm[er] = vmax;
          sri[er] = 1.0f / ss;
        }
      }
    }
    __syncthreads();
    {  // phase 3: emit att16 panel-blocked [b][ep][n(256)][64e] — fully contiguous 32KB
      _Float16* ab = att16 + ((size_t)b * 16 + sep) * 256 * 64;
      int nb = t >> 3, el = (t & 7) * 8;
#pragma unroll
      for (int rep = 0; rep < 8; ++rep) {
        int n = nb + rep * 32;
        float ns = snc[n];
        float4 icv0 = *(const float4*)&inc[(size_t)n * EE + e0p + el];
        float4 icv1 = *(const float4*)&inc[(size_t)n * EE + e0p + el + 4];
        float ica[8] = {icv0.x, icv0.y, icv0.z, icv0.w, icv1.x, icv1.y, icv1.z, icv1.w};
        f16x8 o;
#pragma unroll
        for (int qq = 0; qq < 8; ++qq) {
          float att = 0.f;
          if (ica[qq] > 0.f) {
            float s1v = lrelu(ns + sesc[el + qq]);
            float s2v = lrelu(steA[el + qq] + s1v * a31);
            att = __expf(s2v - srm[el + qq]) * sri[el + qq];
          }
          o[qq] = (_Float16)att;
        }
        *(f16x8*)&ab[(size_t)n * 64 + el] = o;
      }
    }
  }
}

// out0[b,d,n] = sum_e att16[n,e]*out1T16[d,e]; panel-blocked operands; b-pinned XCD
__global__ __launch_bounds__(256) void k_fgemm(const _Float16* __restrict__ att16, const _Float16* __restrict__ out1T,
                                               float* __restrict__ out0) {
  __shared__ _Float16 smA[64 * 64];
  __shared__ _Float16 smB[64 * 64];
  int bid = blockIdx.x;
  int xcd = bid & 7, il = bid >> 3;  // 96 per XCD
  int ntile = il & 3, dtile = (il >> 2) & 3, bl = il >> 4;
  int b = xcd * 6 + bl;
  int n0 = ntile * 64, d0 = dtile * 64;
  int t = threadIdx.x, w = t >> 6, l = t & 63;
  int wm = w >> 1, wn = w & 1;
  int lr = l & 15;
  int lrow = l >> 3;
  int scol = 8 * ((l & 7) ^ (lrow & 7));
  f32x4 acc[2][2];
  f32x4 z = {0.f, 0.f, 0.f, 0.f};
#pragma unroll
  for (int i = 0; i < 2; ++i)
#pragma unroll
    for (int j = 0; j < 2; ++j) acc[i][j] = z;
  for (int kk = 0; kk < EE; kk += 64) {
    int ep = kk >> 6;
    const _Float16* Ak = att16 + (((size_t)b * 16 + ep) * 256 + n0) * 64;
    const _Float16* Bk = out1T + (((size_t)b * 16 + ep) * 256 + d0) * 64;
#pragma unroll
    for (int q = 0; q < 2; ++q) {
      int row = q * 32 + w * 8 + lrow;
      int lb = (q * 32 + w * 8) * 64;
      gload16(Ak + (size_t)row * 64 + scol, smA + lb);
      gload16(Bk + (size_t)row * 64 + scol, smB + lb);
    }
    __syncthreads();
    f16x8 af[2][2], bf[2][2];
#pragma unroll
    for (int i = 0; i < 2; ++i)
#pragma unroll
      for (int ks = 0; ks < 2; ++ks) {
        int ra = wm * 32 + i * 16 + lr;
        af[i][ks] = *(const f16x8*)&smA[ra * 64 + ((ks * 32 + (l >> 4) * 8) ^ ((ra & 7) << 3))];
        int rb = wn * 32 + i * 16 + lr;
        bf[i][ks] = *(const f16x8*)&smB[rb * 64 + ((ks * 32 + (l >> 4) * 8) ^ ((rb & 7) << 3))];
      }
#pragma unroll
    for (int ks = 0; ks < 2; ++ks)
#pragma unroll
      for (int i = 0; i < 2; ++i)
#pragma unroll
        for (int j = 0; j < 2; ++j)
          acc[i][j] = __builtin_amdgcn_mfma_f32_16x16x32_f16(af[i][ks], bf[j][ks], acc[i][j], 0, 0, 0);
    __syncthreads();
  }
  float* ob = out0 + (size_t)b * DD * NN;
#pragma unroll
  for (int i = 0; i < 2; ++i)
#pragma unroll
    for (int j = 0; j < 2; ++j) {
      int n = n0 + wm * 32 + i * 16 + (l >> 4) * 4;
      int d = d0 + wn * 32 + j * 16 + lr;
      f32x4 v;
      v[0] = acc[i][j][0];
      v[1] = acc[i][j][1];
      v[2] = acc[i][j][2];
      v[3] = acc[i][j][3];
      __builtin_nontemporal_store(v, (f32x4*)&ob[(size_t)d * NN + n]);
    }
}

extern "C" void kernel_launch(void* const* d_in, const int* in_sizes, int n_in, void* d_out, int out_size,
                              void* d_ws, size_t ws_size, hipStream_t stream) {
  (void)in_sizes;
  (void)n_in;
  (void)out_size;
  (void)ws_size;
  const float* x = (const float*)d_in[0];
  const float* m = (const float*)d_in[1];
  const float* hid = (const float*)d_in[2];
  const float* pri_e = (const float*)d_in[3];
  const float* inc = (const float*)d_in[5];
  const float* W = (const float*)d_in[6];
  const float* bias = (const float*)d_in[7];
  const float* W2 = (const float*)d_in[8];
  const float* a = (const float*)d_in[9];
  const float* a2 = (const float*)d_in[10];
  const float* a3 = (const float*)d_in[11];

  float* out0 = (float*)d_out;                // [B,D,N]
  float* out1 = out0 + (size_t)BB * DD * NN;  // [B,E,D] fp32 (written by k_out1s)
  _Float16* xt16 = (_Float16*)out1;           // [B,N,CIN] fp16 — dead after k_mid, before out1 written

  _Float16* out1T16 = (_Float16*)d_ws;                  // [B][16][256][64] panel-blocked
  _Float16* hThi = out1T16 + (size_t)BB * DD * EE;      // [B,D,N]
  _Float16* incT = hThi + (size_t)BB * DD * NN;         // [E,N]
  _Float16* w2shi = incT + (size_t)EE * NN;             // [E,E]
  _Float16* w2slo = w2shi + (size_t)EE * EE;            // [E,E]
  _Float16* inc16 = w2slo + (size_t)EE * EE;            // [N,E]
  _Float16* M16 = inc16 + (size_t)NN * EE;              // [E,N]
  _Float16* wt16 = M16 + (size_t)EE * NN;               // [D,CIN]
  _Float16* att16 = wt16 + (size_t)DD * CIN;            // [B][16][256][64] panel-blocked
  float* M32 = (float*)(att16 + (size_t)BB * NN * EE);  // [E,N] fp32
  float* node_sc = M32 + (size_t)EE * NN;               // B*N
  float* g1 = node_sc + (size_t)BB * NN;                // B*N
  float* g2 = g1 + (size_t)BB * NN;                     // B*N
  float* wa = g2 + (size_t)BB * NN;                     // 1024

  k_prep<<<dim3(1376), 256, 0, stream>>>(inc, W2, W, x, m, hid, a, a2, incT, w2shi, w2slo, wt16, inc16, wa, xt16);
  k_mid<<<dim3(880), 256, 0, stream>>>(xt16, wt16, bias, hThi, inc16, w2shi, w2slo, M32, M16, x, m, hid, wa,
                                       node_sc, g1, g2);
  k_out1s<<<dim3(768 + 1536), 256, 0, stream>>>(M16, hThi, out1, out1T16, M32, g1, g2, node_sc, pri_e, a2, a3,
                                                incT, inc, att16);
  k_fgemm<<<dim3(8 * 96), 256, 0, stream>>>(att16, out1T16, out0);
}

// Round 18
// 105.533 us; speedup vs baseline: 1.0111x; 1.0111x over previous
//
#include <hip/hip_runtime.h>

#define BB 48
#define NN 256
#define EE 1024
#define DD 256
#define CIN 256

typedef __attribute__((ext_vector_type(4))) float f32x4;
typedef __attribute__((ext_vector_type(8))) _Float16 f16x8;
typedef __attribute__((ext_vector_type(4))) _Float16 f16x4;

__device__ __forceinline__ float lrelu(float t) { return t >= 0.0f ? t : 0.2f * t; }

__device__ __forceinline__ void gload16(const void* g, void* l) {
  __builtin_amdgcn_global_load_lds((const __attribute__((address_space(1))) void*)g,
                                   (__attribute__((address_space(3))) void*)l, 16, 0, 0);
}

// ---- k_prep: w2s hi/lo, incT, wt16, inc16, wa, xt (all input-only) ----
__global__ __launch_bounds__(256) void k_prep(const float* __restrict__ inc, const float* __restrict__ W2,
                                              const float* __restrict__ W, const float* __restrict__ x,
                                              const float* __restrict__ m, const float* __restrict__ hid,
                                              const float* __restrict__ a, const float* __restrict__ a2,
                                              _Float16* __restrict__ incT, _Float16* __restrict__ w2shi,
                                              _Float16* __restrict__ w2slo, _Float16* __restrict__ wt16,
                                              _Float16* __restrict__ inc16, float* __restrict__ wa,
                                              _Float16* __restrict__ xt) {
  __shared__ float tile[64][65];
  __shared__ float aux[4][64];
  __shared__ float aux2[64];
  int bid = blockIdx.x;
  int t = threadIdx.x;
  if (bid < 256) {  // w2s[e,f] = W2[f,e]*invdeg[f], hi/lo fp16 split
    int f0 = (bid & 15) * 64, e0 = (bid >> 4) * 64;
    int c = t & 63, r = t >> 6;
    {
      float s = 0.f;
      for (int i = 0; i < 64; ++i) s += inc[(size_t)(r * 64 + i) * EE + f0 + c];
      aux[r][c] = s;
    }
#pragma unroll
    for (int i = 0; i < 16; ++i) tile[r + i * 4][c] = W2[(size_t)(f0 + r + i * 4) * EE + e0 + c];
    __syncthreads();
    if (t < 64) aux2[t] = 1.0f / (aux[0][t] + aux[1][t] + aux[2][t] + aux[3][t]);
    __syncthreads();
#pragma unroll
    for (int i = 0; i < 16; ++i) {
      int row = r + i * 4;
      float v = tile[c][row] * aux2[c];
      _Float16 hh = (_Float16)v;
      w2shi[(size_t)(e0 + row) * EE + f0 + c] = hh;
      w2slo[(size_t)(e0 + row) * EE + f0 + c] = (_Float16)(v - (float)hh);
    }
  } else if (bid < 320) {  // incT[e,n] = inc[n,e]
    int s = bid - 256;
    int e0 = (s & 15) * 64, n0 = (s >> 4) * 64;
    int c = t & 63, r = t >> 6;
#pragma unroll
    for (int i = 0; i < 16; ++i) tile[r + i * 4][c] = inc[(size_t)(n0 + r + i * 4) * EE + e0 + c];
    __syncthreads();
#pragma unroll
    for (int i = 0; i < 16; ++i) {
      int row = r + i * 4;
      incT[(size_t)(e0 + row) * NN + n0 + c] = (_Float16)tile[c][row];
    }
  } else if (bid < 336) {  // wt16[d,c] = fp16(W[c,d])
    int s = bid - 320;
    int c0 = (s & 3) * 64, d0 = (s >> 2) * 64;
    int c = t & 63, r = t >> 6;
#pragma unroll
    for (int i = 0; i < 16; ++i) tile[r + i * 4][c] = W[(size_t)(c0 + r + i * 4) * DD + d0 + c];
    __syncthreads();
#pragma unroll
    for (int i = 0; i < 16; ++i) {
      int row = r + i * 4;
      wt16[(size_t)(d0 + row) * CIN + c0 + c] = (_Float16)tile[c][row];
    }
  } else if (bid < 352) {  // inc16[n,f] = fp16(inc) (exact 0/1)
    int s = bid - 336;
    size_t base = ((size_t)s * 256 + t) * 64;
#pragma unroll
    for (int i = 0; i < 16; ++i) {
      f32x4 v = *(const f32x4*)&inc[base + i * 4];
      f16x4 o;
      o[0] = (_Float16)v[0];
      o[1] = (_Float16)v[1];
      o[2] = (_Float16)v[2];
      o[3] = (_Float16)v[3];
      *(f16x4*)&inc16[base + i * 4] = o;
    }
  } else if (bid < 608) {  // wa
    float(*red)[4] = (float(*)[4])aux;
    int c = bid - 352;
    int l = t & 63, wv = t >> 6;
    float w = W[(size_t)c * DD + t];
    float p0 = w * a[t], p1 = w * a[DD + t], p2 = w * a2[t];
#pragma unroll
    for (int off = 32; off > 0; off >>= 1) {
      p0 += __shfl_down(p0, off);
      p1 += __shfl_down(p1, off);
      p2 += __shfl_down(p2, off);
    }
    if (l == 0) {
      red[0][wv] = p0;
      red[1][wv] = p1;
      red[2][wv] = p2;
    }
    __syncthreads();
    if (t == 0) wa[c] = red[0][0] + red[0][1] + red[0][2] + red[0][3];
    if (t == 1) wa[256 + c] = red[1][0] + red[1][1] + red[1][2] + red[1][3];
    if (t == 2) wa[512 + c] = red[2][0] + red[2][1] + red[2][2] + red[2][3];
    if (c == 0) {
      __syncthreads();
      float q0 = a[t], q1 = a[DD + t], q2 = a2[t];
#pragma unroll
      for (int off = 32; off > 0; off >>= 1) {
        q0 += __shfl_down(q0, off);
        q1 += __shfl_down(q1, off);
        q2 += __shfl_down(q2, off);
      }
      if (l == 0) {
        red[0][wv] = q0;
        red[1][wv] = q1;
        red[2][wv] = q2;
      }
      __syncthreads();
      if (t == 0) wa[768] = red[0][0] + red[0][1] + red[0][2] + red[0][3];
      if (t == 1) wa[769] = red[1][0] + red[1][1] + red[1][2] + red[1][3];
      if (t == 2) wa[770] = red[2][0] + red[2][1] + red[2][2] + red[2][3];
    }
  } else {  // xt16[b,n,c] = fp16(x_in[b,c,n]); 768 blocks
    int s = bid - 608;
    int c0 = (s & 3) * 64, n0 = ((s >> 2) & 3) * 64, b = s >> 4;
    int c = t & 63, r = t >> 6;
#pragma unroll
    for (int i = 0; i < 16; ++i) {
      int ch = c0 + r + i * 4;
      const float* row;
      if (ch < 96) row = x + ((size_t)b * 96 + ch) * NN;
      else if (ch < 192) row = m + ((size_t)b * 96 + (ch - 96)) * NN;
      else row = hid + ((size_t)b * 64 + (ch - 192)) * NN;
      tile[r + i * 4][c] = row[n0 + c];
    }
    __syncthreads();
#pragma unroll
    for (int i = 0; i < 16; ++i) {
      int row = r + i * 4;
      xt[((size_t)b * NN + n0 + row) * CIN + c0 + c] = (_Float16)tile[c][row];
    }
  }
}

// ---- k_mid: h16 (768) + M32/M16 2-term split MFMA (64) + ns2 (48) ----
__global__ __launch_bounds__(256) void k_mid(const _Float16* __restrict__ xt, const _Float16* __restrict__ wt,
                                             const float* __restrict__ bias, _Float16* __restrict__ hThi,
                                             const _Float16* __restrict__ inc16, const _Float16* __restrict__ w2shi,
                                             const _Float16* __restrict__ w2slo, float* __restrict__ M32,
                                             _Float16* __restrict__ M16, const float* __restrict__ x,
                                             const float* __restrict__ m, const float* __restrict__ hid,
                                             const float* __restrict__ wa, float* __restrict__ node_sc,
                                             float* __restrict__ g1, float* __restrict__ g2) {
  __shared__ _Float16 smA[64 * 64];
  __shared__ _Float16 smB[64 * 64];
  __shared__ _Float16 smB2[64 * 64];
  int bid = blockIdx.x;
  int t = threadIdx.x;
  if (bid < 768) {  // h16
    int xcd = bid & 7, il = bid >> 3;
    int ntile = il & 3, dtile = (il >> 2) & 3, bl = il >> 4;
    int b = xcd * 6 + bl;
    int n0 = ntile * 64, d0 = dtile * 64;
    int w = t >> 6, l = t & 63;
    int wm = w >> 1, wn = w & 1;
    int lr = l & 15;
    const _Float16* A = xt + ((size_t)b * NN + n0) * CIN;
    const _Float16* Bp = wt + (size_t)d0 * CIN;
    int lrow = l >> 3;
    int scol = 8 * ((l & 7) ^ (lrow & 7));
    f32x4 acc[2][2];
    f32x4 z = {0.f, 0.f, 0.f, 0.f};
#pragma unroll
    for (int i = 0; i < 2; ++i)
#pragma unroll
      for (int j = 0; j < 2; ++j) acc[i][j] = z;
    for (int kk = 0; kk < CIN; kk += 64) {
#pragma unroll
      for (int q = 0; q < 2; ++q) {
        int row = q * 32 + w * 8 + lrow;
        int lb = (q * 32 + w * 8) * 64;
        gload16(A + (size_t)row * CIN + kk + scol, smA + lb);
        gload16(Bp + (size_t)row * CIN + kk + scol, smB + lb);
      }
      __syncthreads();
      f16x8 af[2][2], bf[2][2];
#pragma unroll
      for (int i = 0; i < 2; ++i)
#pragma unroll
        for (int ks = 0; ks < 2; ++ks) {
          int ra = wm * 32 + i * 16 + lr;
          af[i][ks] = *(const f16x8*)&smA[ra * 64 + ((ks * 32 + (l >> 4) * 8) ^ ((ra & 7) << 3))];
          int rb = wn * 32 + i * 16 + lr;
          bf[i][ks] = *(const f16x8*)&smB[rb * 64 + ((ks * 32 + (l >> 4) * 8) ^ ((rb & 7) << 3))];
        }
#pragma unroll
      for (int ks = 0; ks < 2; ++ks)
#pragma unroll
        for (int i = 0; i < 2; ++i)
#pragma unroll
          for (int j = 0; j < 2; ++j)
            acc[i][j] = __builtin_amdgcn_mfma_f32_16x16x32_f16(af[i][ks], bf[j][ks], acc[i][j], 0, 0, 0);
      __syncthreads();
    }
#pragma unroll
    for (int i = 0; i < 2; ++i)
#pragma unroll
      for (int j = 0; j < 2; ++j) {
        int nb = n0 + wm * 32 + i * 16 + (l >> 4) * 4;
        int d = d0 + wn * 32 + j * 16 + lr;
        float4 bv = *(const float4*)&bias[nb];
        f16x4 vh;
        vh[0] = (_Float16)(acc[i][j][0] + bv.x);
        vh[1] = (_Float16)(acc[i][j][1] + bv.y);
        vh[2] = (_Float16)(acc[i][j][2] + bv.z);
        vh[3] = (_Float16)(acc[i][j][3] + bv.w);
        *(f16x4*)&hThi[((size_t)b * DD + d) * NN + nb] = vh;
      }
  } else if (bid < 832) {  // M32/M16[e,n] = sum_f inc16[n,f]*(w2shi+w2slo)[e,f]; 64 blocks
    int mb = bid - 768;
    int np = mb & 3, ep = mb >> 2;
    int m0 = np * 64;
    int n0 = ep * 64;
    int w = t >> 6, l = t & 63;
    int wm = w >> 1, wn = w & 1;
    int lr = l & 15;
    const _Float16* A = inc16 + (size_t)m0 * EE;
    const _Float16* Bh = w2shi + (size_t)n0 * EE;
    const _Float16* Bl = w2slo + (size_t)n0 * EE;
    int lrow = l >> 3;
    int scol = 8 * ((l & 7) ^ (lrow & 7));
    f32x4 acc[2][2];
    f32x4 z = {0.f, 0.f, 0.f, 0.f};
#pragma unroll
    for (int i = 0; i < 2; ++i)
#pragma unroll
      for (int j = 0; j < 2; ++j) acc[i][j] = z;
    for (int kk = 0; kk < EE; kk += 64) {
#pragma unroll
      for (int q = 0; q < 2; ++q) {
        int row = q * 32 + w * 8 + lrow;
        int lb = (q * 32 + w * 8) * 64;
        gload16(A + (size_t)row * EE + kk + scol, smA + lb);
        gload16(Bh + (size_t)row * EE + kk + scol, smB + lb);
        gload16(Bl + (size_t)row * EE + kk + scol, smB2 + lb);
      }
      __syncthreads();
      f16x8 af[2][2], bfh[2][2], bfl[2][2];
#pragma unroll
      for (int i = 0; i < 2; ++i)
#pragma unroll
        for (int ks = 0; ks < 2; ++ks) {
          int ra = wm * 32 + i * 16 + lr;
          int off_a = ra * 64 + ((ks * 32 + (l >> 4) * 8) ^ ((ra & 7) << 3));
          af[i][ks] = *(const f16x8*)&smA[off_a];
          int rb = wn * 32 + i * 16 + lr;
          int off_b = rb * 64 + ((ks * 32 + (l >> 4) * 8) ^ ((rb & 7) << 3));
          bfh[i][ks] = *(const f16x8*)&smB[off_b];
          bfl[i][ks] = *(const f16x8*)&smB2[off_b];
        }
#pragma unroll
      for (int ks = 0; ks < 2; ++ks)
#pragma unroll
        for (int i = 0; i < 2; ++i)
#pragma unroll
          for (int j = 0; j < 2; ++j) {
            acc[i][j] = __builtin_amdgcn_mfma_f32_16x16x32_f16(af[i][ks], bfh[j][ks], acc[i][j], 0, 0, 0);
            acc[i][j] = __builtin_amdgcn_mfma_f32_16x16x32_f16(af[i][ks], bfl[j][ks], acc[i][j], 0, 0, 0);
          }
      __syncthreads();
    }
#pragma unroll
    for (int i = 0; i < 2; ++i)
#pragma unroll
      for (int j = 0; j < 2; ++j) {
        int n = m0 + wm * 32 + i * 16 + (l >> 4) * 4;
        int e = n0 + wn * 32 + j * 16 + lr;
        *(f32x4*)&M32[(size_t)e * NN + n] = acc[i][j];
        f16x4 v;
#pragma unroll
        for (int r = 0; r < 4; ++r) v[r] = (_Float16)acc[i][j][r];
        *(f16x4*)&M16[(size_t)e * NN + n] = v;
      }
  } else {  // ns2: b = bid - 832
    float* s0a = (float*)smA;
    float* s1a = s0a + 256;
    float* s2a = s0a + 512;
    int b = bid - 832;
    s0a[t] = wa[t];
    s1a[t] = wa[256 + t];
    s2a[t] = wa[512 + t];
    __syncthreads();
    float s0 = 0.f, s1 = 0.f, s2 = 0.f;
#pragma unroll 4
    for (int c = 0; c < 256; ++c) {
      const float* row;
      if (c < 96) row = x + ((size_t)b * 96 + c) * NN;
      else if (c < 192) row = m + ((size_t)b * 96 + (c - 96)) * NN;
      else row = hid + ((size_t)b * 64 + (c - 192)) * NN;
      float v = row[t];
      s0 += v * s0a[c];
      s1 += v * s1a[c];
      s2 += v * s2a[c];
    }
    float bv = bias[t];
    int idx = b * NN + t;
    node_sc[idx] = s0 + bv * wa[768];
    g1[idx] = s1 + bv * wa[769];
    g2[idx] = s2 + bv * wa[770];
  }
}

// ---- k_out1s: score/att16 (768 blocks FIRST) + out1/out1T16 GEMM (3072 blocks, BK=128) ----
// att16/out1T16 are PANEL-BLOCKED: [b][ep][n or d][64e] — contiguous per-block writes
__global__ __launch_bounds__(256) void k_out1s(const _Float16* __restrict__ M16, const _Float16* __restrict__ hThi,
                                               float* __restrict__ out1, _Float16* __restrict__ out1T,
                                               const float* __restrict__ M32, const float* __restrict__ g1,
                                               const float* __restrict__ g2, const float* __restrict__ node_sc,
                                               const float* __restrict__ pri_e, const float* __restrict__ a2,
                                               const float* __restrict__ a3, const _Float16* __restrict__ incT,
                                               const float* __restrict__ inc, _Float16* __restrict__ att16) {
  __shared__ _Float16 smA[64 * 128];
  __shared__ _Float16 smB[64 * 128];
  int bid = blockIdx.x;
  int t = threadIdx.x;
  if (bid >= 768) {  // out1[b,e,d] = sum_n M16[e,n]*hThi[b,d,n]; 64e x 64d; BK=128; b-pinned XCD
    int gb = bid - 768;
    int xcd = gb & 7, il = gb >> 3;  // 384 per XCD
    int ep = il & 15, dblk = (il >> 4) & 3, bl = il >> 6;
    int b = xcd * 6 + bl;
    int e0 = ep * 64, d0 = dblk * 64;
    int w = t >> 6, l = t & 63;
    int wm = w >> 1, wn = w & 1;
    int lr = l & 15;
    const _Float16* A = M16 + (size_t)e0 * NN;
    const _Float16* Bp = hThi + ((size_t)b * DD + d0) * NN;
    // staging geometry (BK=128): inst q covers rows q*16 + w*4 + (l>>4); within-row granule l&15
    int srow = w * 4 + (l >> 4);         // row offset within 16-row group
    int chunk = ((l & 15) >> 3) * 64;    // 0 or 64
    int g8 = l & 7;                      // granule within chunk
    f32x4 acc[2][2];
    f32x4 z = {0.f, 0.f, 0.f, 0.f};
#pragma unroll
    for (int i = 0; i < 2; ++i)
#pragma unroll
      for (int j = 0; j < 2; ++j) acc[i][j] = z;
    for (int ko = 0; ko < NN; ko += 128) {
#pragma unroll
      for (int q = 0; q < 4; ++q) {
        int row = q * 16 + srow;
        int scolq = chunk + ((g8 ^ (row & 7)) << 3);
        int lb = (q * 16 + srow) * 128 - srow * 128 + (q * 16 + w * 4 + (l >> 4)) * 0;  // dummy
        // LDS dest is wave-linear: base elem = q*2048 + w*512 + l*8
        gload16(A + (size_t)row * NN + ko + scolq, smA + q * 2048 + w * 512);
        gload16(Bp + (size_t)row * NN + ko + scolq, smB + q * 2048 + w * 512);
      }
      __syncthreads();
      f16x8 af[2][2], bf[2][2];
#pragma unroll
      for (int kc = 0; kc < 2; ++kc) {
#pragma unroll
        for (int i = 0; i < 2; ++i)
#pragma unroll
          for (int ks = 0; ks < 2; ++ks) {
            int ra = wm * 32 + i * 16 + lr;
            af[i][ks] =
                *(const f16x8*)&smA[ra * 128 + kc * 64 + ((ks * 32 + (l >> 4) * 8) ^ ((ra & 7) << 3))];
            int rb = wn * 32 + i * 16 + lr;
            bf[i][ks] =
                *(const f16x8*)&smB[rb * 128 + kc * 64 + ((ks * 32 + (l >> 4) * 8) ^ ((rb & 7) << 3))];
          }
#pragma unroll
        for (int ks = 0; ks < 2; ++ks)
#pragma unroll
          for (int i = 0; i < 2; ++i)
#pragma unroll
            for (int j = 0; j < 2; ++j)
              acc[i][j] = __builtin_amdgcn_mfma_f32_16x16x32_f16(af[i][ks], bf[j][ks], acc[i][j], 0, 0, 0);
      }
      __syncthreads();
    }
    // out1 fp32 direct stores
#pragma unroll
    for (int i = 0; i < 2; ++i)
#pragma unroll
      for (int j = 0; j < 2; ++j) {
        int e = e0 + wm * 32 + i * 16 + (l >> 4) * 4;
        int d = d0 + wn * 32 + j * 16 + lr;
#pragma unroll
        for (int r = 0; r < 4; ++r) out1[((size_t)b * EE + e + r) * DD + d] = acc[i][j][r];
      }
    // out1T16 via LDS -> panel-blocked [b][ep][d(256)][64e]: contiguous 8KB per block
#pragma unroll
    for (int i = 0; i < 2; ++i)
#pragma unroll
      for (int j = 0; j < 2; ++j) {
        int dr = wn * 32 + j * 16 + lr;
        int er = wm * 32 + i * 16 + (l >> 4) * 4;
        f16x4 v16;
#pragma unroll
        for (int r = 0; r < 4; ++r) v16[r] = (_Float16)acc[i][j][r];
        *(f16x4*)&smA[dr * 64 + (er ^ ((dr & 7) << 3))] = v16;
      }
    __syncthreads();
    {
      int dr = t >> 2, ec = (t & 3) * 16;
      _Float16* orow = out1T + (((size_t)b * 16 + ep) * 256 + d0 + dr) * 64;
#pragma unroll
      for (int g = 0; g < 2; ++g) {
        int e8 = ec + g * 8;
        f16x8 v = *(const f16x8*)&smA[dr * 64 + (e8 ^ ((dr & 7) << 3))];
        *(f16x8*)&orow[e8] = v;
      }
    }
  } else {  // score + att16 (dispatched first)
    float* sg1 = (float*)smA;                  // 256
    float* sg2 = sg1 + 256;                    // 256
    float* snc = sg2 + 256;                    // 256
    float(*r1)[4] = (float(*)[4])(snc + 256);  // 64*4
    float(*r2)[4] = r1 + 64;                   // 64*4
    float* sesc = (float*)(r2 + 64);           // 64
    float* steA = sesc + 64;                   // 64
    float* srm = steA + 64;                    // 64
    float* sri = srm + 64;                     // 64
    int sb = bid;
    int sep = sb & 15;
    int e0p = sep * 64, b = sb >> 4;
    float a30 = a3[0], a31 = a3[1];
    sg1[t] = g1[b * NN + t];
    sg2[t] = g2[b * NN + t];
    snc[t] = node_sc[b * NN + t];
    __syncthreads();
    {  // phase 1: esc/te for 64 e's (fp32-exact via M32)
      int ei = t >> 2, part = t & 3;
      const float* Mr = M32 + (size_t)(e0p + ei) * NN + part * 64;
      const float* pg1 = sg1 + part * 64;
      const float* pg2 = sg2 + part * 64;
      float s1 = 0.f, s2 = 0.f;
      for (int i = 0; i < 64; i += 4) {
        f32x4 mv = *(const f32x4*)&Mr[i];
        f32x4 v1 = *(const f32x4*)&pg1[i];
        f32x4 v2 = *(const f32x4*)&pg2[i];
        s1 += mv[0] * v1[0] + mv[1] * v1[1] + mv[2] * v1[2] + mv[3] * v1[3];
        s2 += mv[0] * v2[0] + mv[1] * v2[1] + mv[2] * v2[2] + mv[3] * v2[3];
      }
      r1[ei][part] = s1;
      r2[ei][part] = s2;
    }
    __syncthreads();
    if (t < 64) {
      int row = b * EE + e0p + t;
      float es = r1[t][0] + r1[t][1] + r1[t][2] + r1[t][3];
      float te = lrelu(r2[t][0] + r2[t][1] + r2[t][2] + r2[t][3] + pri_e[row] * a2[DD]);
      sesc[t] = es;
      steA[t] = te * a30;
    }
    __syncthreads();
    {  // phase 2: masked max + exp-sum per e (wave per row)
      int w = t >> 6, l = t & 63;
      for (int rr = 0; rr < 16; ++rr) {
        int er = w * 16 + rr;
        int e = e0p + er;
        float es = sesc[er], ta = steA[er];
        f16x4 ic = *(const f16x4*)&incT[(size_t)e * NN + l * 4];
        float s2v[4];
        bool msk[4];
        float vmax = -3.0e38f;
#pragma unroll
        for (int q = 0; q < 4; ++q) {
          float s1 = lrelu(snc[l * 4 + q] + es);
          float s2 = lrelu(ta + s1 * a31);
          msk[q] = (float)ic[q] > 0.f;
          s2v[q] = s2;
          if (msk[q]) vmax = fmaxf(vmax, s2);
        }
#pragma unroll
        for (int off = 32; off > 0; off >>= 1) vmax = fmaxf(vmax, __shfl_xor(vmax, off));
        float ss = 0.f;
#pragma unroll
        for (int q = 0; q < 4; ++q)
          if (msk[q]) ss += __expf(s2v[q] - vmax);
#pragma unroll
        for (int off = 32; off > 0; off >>= 1) ss += __shfl_xor(ss, off);
        if (l == 0) {
          srm[er] = vmax;
          sri[er] = 1.0f / ss;
        }
      }
    }
    __syncthreads();
    {  // phase 3: emit att16 panel-blocked [b][ep][n(256)][64e] — fully contiguous 32KB
      _Float16* ab = att16 + ((size_t)b * 16 + sep) * 256 * 64;
      int nb = t >> 3, el = (t & 7) * 8;
#pragma unroll
      for (int rep = 0; rep < 8; ++rep) {
        int n = nb + rep * 32;
        float ns = snc[n];
        float4 icv0 = *(const float4*)&inc[(size_t)n * EE + e0p + el];
        float4 icv1 = *(const float4*)&inc[(size_t)n * EE + e0p + el + 4];
        float ica[8] = {icv0.x, icv0.y, icv0.z, icv0.w, icv1.x, icv1.y, icv1.z, icv1.w};
        f16x8 o;
#pragma unroll
        for (int qq = 0; qq < 8; ++qq) {
          float att = 0.f;
          if (ica[qq] > 0.f) {
            float s1v = lrelu(ns + sesc[el + qq]);
            float s2v = lrelu(steA[el + qq] + s1v * a31);
            att = __expf(s2v - srm[el + qq]) * sri[el + qq];
          }
          o[qq] = (_Float16)att;
        }
        *(f16x8*)&ab[(size_t)n * 64 + el] = o;
      }
    }
  }
}

// out0[b,d,n] = sum_e att16[n,e]*out1T16[d,e]; panel-blocked operands; b-pinned XCD
__global__ __launch_bounds__(256) void k_fgemm(const _Float16* __restrict__ att16, const _Float16* __restrict__ out1T,
                                               float* __restrict__ out0) {
  __shared__ _Float16 smA[64 * 64];
  __shared__ _Float16 smB[64 * 64];
  int bid = blockIdx.x;
  int xcd = bid & 7, il = bid >> 3;  // 96 per XCD
  int ntile = il & 3, dtile = (il >> 2) & 3, bl = il >> 4;
  int b = xcd * 6 + bl;
  int n0 = ntile * 64, d0 = dtile * 64;
  int t = threadIdx.x, w = t >> 6, l = t & 63;
  int wm = w >> 1, wn = w & 1;
  int lr = l & 15;
  int lrow = l >> 3;
  int scol = 8 * ((l & 7) ^ (lrow & 7));
  f32x4 acc[2][2];
  f32x4 z = {0.f, 0.f, 0.f, 0.f};
#pragma unroll
  for (int i = 0; i < 2; ++i)
#pragma unroll
    for (int j = 0; j < 2; ++j) acc[i][j] = z;
  for (int kk = 0; kk < EE; kk += 64) {
    int ep = kk >> 6;
    const _Float16* Ak = att16 + (((size_t)b * 16 + ep) * 256 + n0) * 64;
    const _Float16* Bk = out1T + (((size_t)b * 16 + ep) * 256 + d0) * 64;
#pragma unroll
    for (int q = 0; q < 2; ++q) {
      int row = q * 32 + w * 8 + lrow;
      int lb = (q * 32 + w * 8) * 64;
      gload16(Ak + (size_t)row * 64 + scol, smA + lb);
      gload16(Bk + (size_t)row * 64 + scol, smB + lb);
    }
    __syncthreads();
    f16x8 af[2][2], bf[2][2];
#pragma unroll
    for (int i = 0; i < 2; ++i)
#pragma unroll
      for (int ks = 0; ks < 2; ++ks) {
        int ra = wm * 32 + i * 16 + lr;
        af[i][ks] = *(const f16x8*)&smA[ra * 64 + ((ks * 32 + (l >> 4) * 8) ^ ((ra & 7) << 3))];
        int rb = wn * 32 + i * 16 + lr;
        bf[i][ks] = *(const f16x8*)&smB[rb * 64 + ((ks * 32 + (l >> 4) * 8) ^ ((rb & 7) << 3))];
      }
#pragma unroll
    for (int ks = 0; ks < 2; ++ks)
#pragma unroll
      for (int i = 0; i < 2; ++i)
#pragma unroll
        for (int j = 0; j < 2; ++j)
          acc[i][j] = __builtin_amdgcn_mfma_f32_16x16x32_f16(af[i][ks], bf[j][ks], acc[i][j], 0, 0, 0);
    __syncthreads();
  }
  float* ob = out0 + (size_t)b * DD * NN;
#pragma unroll
  for (int i = 0; i < 2; ++i)
#pragma unroll
    for (int j = 0; j < 2; ++j) {
      int n = n0 + wm * 32 + i * 16 + (l >> 4) * 4;
      int d = d0 + wn * 32 + j * 16 + lr;
      *(float4*)&ob[(size_t)d * NN + n] =
          make_float4(acc[i][j][0], acc[i][j][1], acc[i][j][2], acc[i][j][3]);
    }
}

extern "C" void kernel_launch(void* const* d_in, const int* in_sizes, int n_in, void* d_out, int out_size,
                              void* d_ws, size_t ws_size, hipStream_t stream) {
  (void)in_sizes;
  (void)n_in;
  (void)out_size;
  (void)ws_size;
  const float* x = (const float*)d_in[0];
  const float* m = (const float*)d_in[1];
  const float* hid = (const float*)d_in[2];
  const float* pri_e = (const float*)d_in[3];
  const float* inc = (const float*)d_in[5];
  const float* W = (const float*)d_in[6];
  const float* bias = (const float*)d_in[7];
  const float* W2 = (const float*)d_in[8];
  const float* a = (const float*)d_in[9];
  const float* a2 = (const float*)d_in[10];
  const float* a3 = (const float*)d_in[11];

  float* out0 = (float*)d_out;                // [B,D,N]
  float* out1 = out0 + (size_t)BB * DD * NN;  // [B,E,D] fp32 (written by k_out1s)
  _Float16* xt16 = (_Float16*)out1;           // [B,N,CIN] fp16 — dead after k_mid, before out1 written

  _Float16* out1T16 = (_Float16*)d_ws;                  // [B][16][256][64] panel-blocked
  _Float16* hThi = out1T16 + (size_t)BB * DD * EE;      // [B,D,N]
  _Float16* incT = hThi + (size_t)BB * DD * NN;         // [E,N]
  _Float16* w2shi = incT + (size_t)EE * NN;             // [E,E]
  _Float16* w2slo = w2shi + (size_t)EE * EE;            // [E,E]
  _Float16* inc16 = w2slo + (size_t)EE * EE;            // [N,E]
  _Float16* M16 = inc16 + (size_t)NN * EE;              // [E,N]
  _Float16* wt16 = M16 + (size_t)EE * NN;               // [D,CIN]
  _Float16* att16 = wt16 + (size_t)DD * CIN;            // [B][16][256][64] panel-blocked
  float* M32 = (float*)(att16 + (size_t)BB * NN * EE);  // [E,N] fp32
  float* node_sc = M32 + (size_t)EE * NN;               // B*N
  float* g1 = node_sc + (size_t)BB * NN;                // B*N
  float* g2 = g1 + (size_t)BB * NN;                     // B*N
  float* wa = g2 + (size_t)BB * NN;                     // 1024

  k_prep<<<dim3(1376), 256, 0, stream>>>(inc, W2, W, x, m, hid, a, a2, incT, w2shi, w2slo, wt16, inc16, wa, xt16);
  k_mid<<<dim3(880), 256, 0, stream>>>(xt16, wt16, bias, hThi, inc16, w2shi, w2slo, M32, M16, x, m, hid, wa,
                                       node_sc, g1, g2);
  k_out1s<<<dim3(768 + 3072), 256, 0, stream>>>(M16, hThi, out1, out1T16, M32, g1, g2, node_sc, pri_e, a2, a3,
                                                incT, inc, att16);
  k_fgemm<<<dim3(8 * 96), 256, 0, stream>>>(att16, out1T16, out0);
}